// Round 7
// baseline (237.770 us; speedup 1.0000x reference)
//
#include <hip/hip_runtime.h>

#define BB 16
#define NN 512
#define DD 256
#define HH 8
#define CC 16

typedef unsigned short u16;
using short8 = __attribute__((ext_vector_type(8))) short;
using f32x4  = __attribute__((ext_vector_type(4))) float;

__device__ __forceinline__ float gelu_f(float x) {
    return 0.5f * x * (1.0f + erff(x * 0.70710678118654752f));
}
__device__ __forceinline__ u16 f2bf(float f) {
    unsigned int u = __float_as_uint(f);
    unsigned int r = u + 0x7FFFu + ((u >> 16) & 1u);
    return (u16)(r >> 16);
}
// async global->LDS, 16B/lane; LDS dest = wave-uniform base + lane*16
__device__ __forceinline__ void gld16(const u16* g, const u16* l) {
    __builtin_amdgcn_global_load_lds(
        (const __attribute__((address_space(1))) unsigned int*)g,
        (__attribute__((address_space(3))) unsigned int*)l, 16, 0, 0);
}

// Q pre-scale: (1/sqrt(32)) * log2(e) -> attention uses exp2
#define QSCALE 0.25505412f

// ---------------------------------------------------------------------------
// QKV GEMM, 128x64 tiles, BK=32. grid (64, 12); sel = y>>2 picks Q/K/V.
// AFP32=1: A is fp32 (emb), converted to bf16 during staging.
// Outputs: Q,K head-major [b,h,n,32] (Q scaled), V transposed [b,h,32,n].
// ---------------------------------------------------------------------------
template<int AFP32>
__global__ __launch_bounds__(256) void gemm_qkv128(
    const void* __restrict__ Av,
    const u16* __restrict__ W0, const u16* __restrict__ W1, const u16* __restrict__ W2,
    u16* __restrict__ O0, u16* __restrict__ O1, u16* __restrict__ O2)
{
    __shared__ __align__(16) u16 As[128 * 32];
    __shared__ __align__(16) u16 Bs[64 * 32];
    const int tid = threadIdx.x, wave = tid >> 6, lane = tid & 63;
    const int col = lane & 15, quad = lane >> 4;
    const int mbase = blockIdx.x * 128;
    const int sel = blockIdx.y >> 2;
    const int nbase = (blockIdx.y & 3) * 64;
    const u16* W = (sel == 0) ? W0 : ((sel == 1) ? W1 : W2);
    u16* O = (sel == 0) ? O0 : ((sel == 1) ? O1 : O2);
    const int srow = lane >> 2, skk = (lane & 3) * 8;
    const int mh = (wave & 1) * 64, nh = (wave >> 1) * 32;

    f32x4 acc[4][2];
#pragma unroll
    for (int i = 0; i < 4; ++i)
#pragma unroll
        for (int j = 0; j < 2; ++j) acc[i][j] = (f32x4){0.f, 0.f, 0.f, 0.f};

    for (int k0 = 0; k0 < DD; k0 += 32) {
        if (AFP32) {
            const float* Af = (const float*)Av;
            const int row = tid >> 1, half = tid & 1;
            const float* src = Af + (size_t)(mbase + row) * DD + k0 + half * 16;
            ushort4 w0, w1, w2, w3;
            float4 v;
            v = *(const float4*)(src + 0);
            w0.x = f2bf(v.x); w0.y = f2bf(v.y); w0.z = f2bf(v.z); w0.w = f2bf(v.w);
            v = *(const float4*)(src + 4);
            w1.x = f2bf(v.x); w1.y = f2bf(v.y); w1.z = f2bf(v.z); w1.w = f2bf(v.w);
            v = *(const float4*)(src + 8);
            w2.x = f2bf(v.x); w2.y = f2bf(v.y); w2.z = f2bf(v.z); w2.w = f2bf(v.w);
            v = *(const float4*)(src + 12);
            w3.x = f2bf(v.x); w3.y = f2bf(v.y); w3.z = f2bf(v.z); w3.w = f2bf(v.w);
            *(ushort4*)&As[row * 32 + half * 16 + 0]  = w0;
            *(ushort4*)&As[row * 32 + half * 16 + 4]  = w1;
            *(ushort4*)&As[row * 32 + half * 16 + 8]  = w2;
            *(ushort4*)&As[row * 32 + half * 16 + 12] = w3;
        } else {
            const u16* Ab = (const u16*)Av;
#pragma unroll
            for (int c = 0; c < 2; ++c) {
                const int ch = wave * 2 + c;
                gld16(Ab + (size_t)(mbase + ch * 16 + srow) * DD + k0 + skk, &As[ch * 512]);
            }
        }
        gld16(W + (size_t)(nbase + wave * 16 + srow) * DD + k0 + skk, &Bs[wave * 512]);
        __syncthreads();
        short8 af[4], bfr[2];
#pragma unroll
        for (int i = 0; i < 4; ++i) af[i]  = *(const short8*)&As[(mh + i * 16 + col) * 32 + quad * 8];
#pragma unroll
        for (int j = 0; j < 2; ++j) bfr[j] = *(const short8*)&Bs[(nh + j * 16 + col) * 32 + quad * 8];
#pragma unroll
        for (int i = 0; i < 4; ++i)
#pragma unroll
            for (int j = 0; j < 2; ++j)
                acc[i][j] = __builtin_amdgcn_mfma_f32_16x16x32_bf16(af[i], bfr[j], acc[i][j], 0, 0, 0);
        __syncthreads();
    }

    const int b = mbase >> 9;
#pragma unroll
    for (int i = 0; i < 4; ++i) {
#pragma unroll
        for (int j = 0; j < 2; ++j) {
            const int ccol = nbase + nh + j * 16 + col;
            const int tok0 = (mbase & 511) + mh + i * 16 + quad * 4;
            const int head = ccol >> 5, dk = ccol & 31;
            if (sel == 2) {
                ushort4 pk;
                pk.x = f2bf(acc[i][j][0]); pk.y = f2bf(acc[i][j][1]);
                pk.z = f2bf(acc[i][j][2]); pk.w = f2bf(acc[i][j][3]);
                *(ushort4*)&O[(((size_t)b * HH + head) * 32 + dk) * NN + tok0] = pk;
            } else {
#pragma unroll
                for (int r = 0; r < 4; ++r) {
                    float v = acc[i][j][r];
                    if (sel == 0) v *= QSCALE;
                    O[(((size_t)b * HH + head) * NN + tok0 + r) * 32 + dk] = f2bf(v);
                }
            }
        }
    }
}

// ---------------------------------------------------------------------------
// Generic 64x64-tile bf16 MFMA GEMM (BK=32). grid (128, 4).
// AG: 0 = A bf16 (gld16), 2 = A fp32 with gelu applied during staging.
// ---------------------------------------------------------------------------
template<int ACT, int HAS_B, int HAS_T, int OUT_F32, int AG>
__global__ __launch_bounds__(256) void gemm64(
    const void* __restrict__ Av, const u16* __restrict__ W,
    u16* __restrict__ O, float* __restrict__ OF,
    const float* __restrict__ bias, const float* __restrict__ tvec)
{
    __shared__ __align__(16) u16 As[64 * 32];
    __shared__ __align__(16) u16 Bs[64 * 32];
    const int tid = threadIdx.x, wave = tid >> 6, lane = tid & 63;
    const int col = lane & 15, quad = lane >> 4;
    const int mbase = blockIdx.x * 64;
    const int nbase = blockIdx.y * 64;
    const int srow = lane >> 2, skk = (lane & 3) * 8;
    const int mh = (wave & 1) * 32, nh = (wave >> 1) * 32;

    f32x4 acc[2][2];
#pragma unroll
    for (int i = 0; i < 2; ++i)
#pragma unroll
        for (int j = 0; j < 2; ++j) acc[i][j] = (f32x4){0.f, 0.f, 0.f, 0.f};

    for (int k0 = 0; k0 < DD; k0 += 32) {
        if (AG) {
            const float* Af = (const float*)Av;
            const int row = tid >> 2, kq = tid & 3;
            const float* src = Af + (size_t)(mbase + row) * DD + k0 + kq * 8;
            float4 v0 = *(const float4*)(src + 0);
            float4 v1 = *(const float4*)(src + 4);
            ushort4 w0, w1;
            w0.x = f2bf(gelu_f(v0.x)); w0.y = f2bf(gelu_f(v0.y));
            w0.z = f2bf(gelu_f(v0.z)); w0.w = f2bf(gelu_f(v0.w));
            w1.x = f2bf(gelu_f(v1.x)); w1.y = f2bf(gelu_f(v1.y));
            w1.z = f2bf(gelu_f(v1.z)); w1.w = f2bf(gelu_f(v1.w));
            *(ushort4*)&As[row * 32 + kq * 8 + 0] = w0;
            *(ushort4*)&As[row * 32 + kq * 8 + 4] = w1;
        } else {
            const u16* Ab = (const u16*)Av;
            gld16(Ab + (size_t)(mbase + wave * 16 + srow) * DD + k0 + skk, &As[wave * 512]);
        }
        gld16(W + (size_t)(nbase + wave * 16 + srow) * DD + k0 + skk, &Bs[wave * 512]);
        __syncthreads();
        short8 af[2], bfr[2];
#pragma unroll
        for (int i = 0; i < 2; ++i) af[i]  = *(const short8*)&As[(mh + i * 16 + col) * 32 + quad * 8];
#pragma unroll
        for (int j = 0; j < 2; ++j) bfr[j] = *(const short8*)&Bs[(nh + j * 16 + col) * 32 + quad * 8];
#pragma unroll
        for (int i = 0; i < 2; ++i)
#pragma unroll
            for (int j = 0; j < 2; ++j)
                acc[i][j] = __builtin_amdgcn_mfma_f32_16x16x32_bf16(af[i], bfr[j], acc[i][j], 0, 0, 0);
        __syncthreads();
    }

    const int b = mbase >> 9;
#pragma unroll
    for (int i = 0; i < 2; ++i) {
#pragma unroll
        for (int j = 0; j < 2; ++j) {
            const int ccol = nbase + nh + j * 16 + col;
#pragma unroll
            for (int r = 0; r < 4; ++r) {
                const int crow = mbase + mh + i * 16 + quad * 4 + r;
                float v = acc[i][j][r];
                if (HAS_B) v += bias[ccol];
                if (HAS_T) v += tvec[b * DD + ccol];
                if (ACT)   v = gelu_f(v);
                if (OUT_F32) OF[(size_t)crow * DD + ccol] = v;
                else         O[(size_t)crow * DD + ccol] = f2bf(v);
            }
        }
    }
}

// ---------------------------------------------------------------------------
// Flash MFMA attention v2: K and V^T fragments straight from L2 (no V LDS
// staging, no staging barrier; LDS = per-wave P chunk only, ~6 KB).
// No-max softmax (pre-scaled by log2e/sqrt(dk), exp2).
// grid 1024: gid = qb*128 + (b*8+h) -> q-blocks of a (b,h) share an XCD.
// COLSUM=1: only writes per-block column sums (feeds mean(x2)@Wo1).
// ---------------------------------------------------------------------------
template<int COLSUM>
__global__ __launch_bounds__(256, 4) void attn_mfma(
    const u16* __restrict__ Qh, const u16* __restrict__ Kh,
    const u16* __restrict__ VT, u16* __restrict__ O,
    float* __restrict__ partial)
{
    __shared__ __align__(16) u16 Pc[4][16 * 40];   // stride 40: 4-way max
    __shared__ float cs[4][32];
    const int tid = threadIdx.x, wave = tid >> 6, lane = tid & 63;
    const int col = lane & 15, quad = lane >> 4;
    const int gid = blockIdx.x;
    const int qb = gid >> 7, bh = gid & 127;
    const int q0 = qb * 64 + wave * 16;

    const short8 aq = *(const short8*)(Qh + ((size_t)bh * NN + q0 + col) * 32 + quad * 8);
    const u16* ksrc = Kh + (size_t)bh * NN * 32;
    const u16* vsrc = VT + (size_t)bh * 32 * NN;

    float l[4] = {0.f, 0.f, 0.f, 0.f};
    f32x4 oacc[2];
    oacc[0] = (f32x4){0.f, 0.f, 0.f, 0.f};
    oacc[1] = (f32x4){0.f, 0.f, 0.f, 0.f};

    u16* pw = &Pc[wave][0];

#pragma unroll 4
    for (int g = 0; g < 16; ++g) {
#pragma unroll
        for (int k2 = 0; k2 < 2; ++k2) {
            const int kt = g * 2 + k2;
            const short8 bk = *(const short8*)(ksrc + (size_t)(kt * 16 + col) * 32 + quad * 8);
            f32x4 z = {0.f, 0.f, 0.f, 0.f};
            const f32x4 s = __builtin_amdgcn_mfma_f32_16x16x32_bf16(aq, bk, z, 0, 0, 0);
#pragma unroll
            for (int r = 0; r < 4; ++r) {
                const float p = exp2f(s[r]);
                l[r] += p;
                pw[(quad * 4 + r) * 40 + k2 * 16 + col] = f2bf(p);
            }
        }
        const short8 ap = *(const short8*)&pw[col * 40 + quad * 8];
#pragma unroll
        for (int nt = 0; nt < 2; ++nt) {
            const short8 bv = *(const short8*)(vsrc + (size_t)(nt * 16 + col) * NN + g * 32 + quad * 8);
            oacc[nt] = __builtin_amdgcn_mfma_f32_16x16x32_bf16(ap, bv, oacc[nt], 0, 0, 0);
        }
    }
#pragma unroll
    for (int r = 0; r < 4; ++r) {
        l[r] += __shfl_xor(l[r], 1, 64);
        l[r] += __shfl_xor(l[r], 2, 64);
        l[r] += __shfl_xor(l[r], 4, 64);
        l[r] += __shfl_xor(l[r], 8, 64);
    }
    if (COLSUM) {
        float sv[2] = {0.f, 0.f};
#pragma unroll
        for (int nt = 0; nt < 2; ++nt) {
#pragma unroll
            for (int r = 0; r < 4; ++r) sv[nt] += oacc[nt][r] / l[r];
            sv[nt] += __shfl_xor(sv[nt], 16, 64);
            sv[nt] += __shfl_xor(sv[nt], 32, 64);
        }
        if (lane < 16) { cs[wave][col] = sv[0]; cs[wave][16 + col] = sv[1]; }
        __syncthreads();
        if (tid < 32)
            partial[(size_t)(bh * 8 + qb) * 32 + tid] =
                cs[0][tid] + cs[1][tid] + cs[2][tid] + cs[3][tid];
    } else {
        const int b = bh >> 3, h = bh & 7;
        u16* obase = O + ((size_t)b * NN) * DD + h * 32;
#pragma unroll
        for (int nt = 0; nt < 2; ++nt)
#pragma unroll
            for (int r = 0; r < 4; ++r)
                obase[(size_t)(q0 + quad * 4 + r) * DD + nt * 16 + col] = f2bf(oacc[nt][r] / l[r]);
    }
}

// ---------------------------------------------------------------------------
// weights -> bf16, transposed [n][k]. grid 144 = 9 weights x 16 k-blocks.
// ---------------------------------------------------------------------------
__global__ __launch_bounds__(256) void convert_w(
    const float* s0, const float* s1, const float* s2, const float* s3,
    const float* s4, const float* s5, const float* s6, const float* s7,
    const float* s8, u16* __restrict__ Wt)
{
    const int w = blockIdx.x;
    const int my = w >> 4, kb = (w & 15) * 16;
    const int n = threadIdx.x;
    const float* S;
    switch (my) {
        case 0: S = s0; break; case 1: S = s1; break; case 2: S = s2; break;
        case 3: S = s3; break; case 4: S = s4; break; case 5: S = s5; break;
        case 6: S = s6; break; case 7: S = s7; break; default: S = s8; break;
    }
    u16* Dst = Wt + (size_t)my * 65536;
    for (int r = 0; r < 16; ++r) {
        const int k = kb + r;
        Dst[(size_t)n * 256 + k] = f2bf(S[(size_t)k * 256 + n]);
    }
}

// ---------------------------------------------------------------------------
// latency-unrolled matvec: 8 independent accumulator chains
// ---------------------------------------------------------------------------
__device__ __forceinline__ float mv256(const float* __restrict__ a,
                                       const float* __restrict__ W, int d)
{
    float acc[8] = {0.f, 0.f, 0.f, 0.f, 0.f, 0.f, 0.f, 0.f};
    for (int k = 0; k < 256; k += 8) {
#pragma unroll
        for (int j = 0; j < 8; ++j)
            acc[j] += a[k + j] * W[(size_t)(k + j) * 256 + d];
    }
    return ((acc[0] + acc[1]) + (acc[2] + acc[3])) + ((acc[4] + acc[5]) + (acc[6] + acc[7]));
}

__global__ __launch_bounds__(256) void aggr_v2(
    const float* __restrict__ partial, const float* __restrict__ Wo1f,
    const float* __restrict__ resW, const float* __restrict__ resb,
    const float* __restrict__ W1, const int* __restrict__ labels,
    float* __restrict__ tvec, float* __restrict__ counts)
{
    const int b = blockIdx.x, d = threadIdx.x;
    __shared__ float a0[256], a1[256], a2[256];
    __shared__ int hist[CC];
    if (d < CC) hist[d] = 0;
    const int h = d >> 5, d32 = d & 31;
    float s = 0.f;
#pragma unroll
    for (int qb = 0; qb < 8; ++qb)
        s += partial[(size_t)(((b * 8 + h) * 8) + qb) * 32 + d32];
    a0[d] = s * (1.0f / NN);
    __syncthreads();
    atomicAdd(&hist[labels[b * NN + d]], 1);
    atomicAdd(&hist[labels[b * NN + 256 + d]], 1);
    a1[d] = gelu_f(mv256(a0, Wo1f, d));
    __syncthreads();
    a2[d] = gelu_f(mv256(a1, resW, d) + resb[d]);
    __syncthreads();
    tvec[b * 256 + d] = mv256(a2, W1, d);
    if (d < CC) counts[b * CC + d] = (float)hist[d];
}

__global__ __launch_bounds__(256) void classsum_v2(
    const float* __restrict__ F, const int* __restrict__ labels,
    float* __restrict__ g)
{
    const int b = blockIdx.x, dch = blockIdx.y;
    const int t = threadIdx.x, w = t >> 6, lane = t & 63;
    __shared__ int lab[NN];
    __shared__ float gs[4][CC][64];
    lab[t] = labels[b * NN + t];
    lab[t + 256] = labels[b * NN + t + 256];
    __syncthreads();
    float acc[CC];
#pragma unroll
    for (int c = 0; c < CC; ++c) acc[c] = 0.f;
    const float* Fb = F + (size_t)b * NN * DD + dch * 64 + lane;
#pragma unroll 4
    for (int n = w * 128; n < w * 128 + 128; ++n) {
        const float v = Fb[(size_t)n * DD];
        const int lb = lab[n];
#pragma unroll
        for (int c = 0; c < CC; ++c) acc[c] += (lb == c) ? v : 0.f;
    }
#pragma unroll
    for (int c = 0; c < CC; ++c) gs[w][c][lane] = acc[c];
    __syncthreads();
#pragma unroll
    for (int i = 0; i < 4; ++i) {
        const int c = w * 4 + i;
        g[((size_t)b * CC + c) * DD + dch * 64 + lane] =
            gs[0][c][lane] + gs[1][c][lane] + gs[2][c][lane] + gs[3][c][lane];
    }
}

__global__ __launch_bounds__(256) void out_kernel(
    const float* __restrict__ F, const int* __restrict__ labels,
    const float* __restrict__ g, const float* __restrict__ counts,
    float* __restrict__ out)
{
    const int b = blockIdx.y;
    const int wave = threadIdx.x >> 6, lane = threadIdx.x & 63;
    const int n = blockIdx.x * 4 + wave;
    const float* fn = F + ((size_t)b * NN + n) * DD;
    const float* gb = g + (size_t)b * CC * DD;
    float fv[4];
#pragma unroll
    for (int i = 0; i < 4; ++i) fv[i] = fn[lane * 4 + i];
    float selfdot = 0.f;
#pragma unroll
    for (int i = 0; i < 4; ++i) selfdot += fv[i] * fv[i];
    float accs[CC];
#pragma unroll
    for (int c = 0; c < CC; ++c) {
        float sacc = 0.f;
#pragma unroll
        for (int i = 0; i < 4; ++i) sacc += fv[i] * gb[c * DD + lane * 4 + i];
        accs[c] = sacc;
    }
    for (int off = 32; off; off >>= 1) {
        selfdot += __shfl_xor(selfdot, off, 64);
#pragma unroll
        for (int c = 0; c < CC; ++c) accs[c] += __shfl_xor(accs[c], off, 64);
    }
    if (lane < CC) {
        const int c = lane;
        const int same = (labels[b * NN + n] == c) ? 1 : 0;
        const float num = accs[c] - (same ? selfdot : 0.f);
        const float den = counts[b * CC + c] - (float)same;
        out[((size_t)b * NN + n) * CC + c] = num / den;
    }
}

// ---------------------------------------------------------------------------
extern "C" void kernel_launch(void* const* d_in, const int* in_sizes, int n_in,
                              void* d_out, int out_size, void* d_ws, size_t ws_size,
                              hipStream_t stream)
{
    const float* emb    = (const float*)d_in[0];
    const int*   labels = (const int*)  d_in[1];
    const float* Wo1f = (const float*)d_in[9];
    const float* resW = (const float*)d_in[10];
    const float* resb = (const float*)d_in[11];
    const float* ffW1 = (const float*)d_in[12];
    const float* ffb1 = (const float*)d_in[13];
    const float* ffb2 = (const float*)d_in[15];
    float* out = (float*)d_out;

    const size_t SBE = (size_t)BB * NN * DD;
    u16* BUF0 = (u16*)d_ws;          // X1
    u16* BUF2 = BUF0 + SBE;          // Qh [b,h,n,32]
    u16* BUF3 = BUF2 + SBE;          // Kh, later H
    u16* BUF4 = BUF3 + SBE;          // VT [b,h,32,n]
    u16* BUF5 = BUF4 + SBE;          // attn0 out (token-major)
    u16* Wt   = BUF5 + SBE;          // 9 x [256n x 256k] bf16 transposed
    float* F      = (float*)(Wt + 9 * 65536);   // [8192x256] fp32 features
    float* tvec   = F + SBE;
    float* partial= tvec + BB * 256;            // [128 bh][8 qb][32]
    float* gsum   = partial + 128 * 8 * 32;
    float* counts = gsum + (size_t)BB * CC * DD;

    convert_w<<<144, 256, 0, stream>>>(
        (const float*)d_in[2], (const float*)d_in[3], (const float*)d_in[4],
        (const float*)d_in[5], (const float*)d_in[6], (const float*)d_in[7],
        (const float*)d_in[8], ffW1 + 256 * 256, (const float*)d_in[14], Wt);
    // QKV0 (A = emb fp32, converted in staging)
    gemm_qkv128<1><<<dim3(64, 12), 256, 0, stream>>>(
        emb, Wt, Wt + 65536, Wt + 2 * 65536, BUF2, BUF3, BUF4);
    attn_mfma<0><<<1024, 256, 0, stream>>>(BUF2, BUF3, BUF4, BUF5, nullptr);
    // X1 = gelu(attn0 @ Wo0) -> BUF0
    gemm64<1,0,0,0,0><<<dim3(128, 4), 256, 0, stream>>>(
        BUF5, Wt + 3 * 65536, BUF0, nullptr, nullptr, nullptr);
    // QKV1
    gemm_qkv128<0><<<dim3(64, 12), 256, 0, stream>>>(
        BUF0, Wt + 4 * 65536, Wt + 5 * 65536, Wt + 6 * 65536, BUF2, BUF3, BUF4);
    // attn1: column sums only
    attn_mfma<1><<<1024, 256, 0, stream>>>(BUF2, BUF3, BUF4, nullptr, partial);
    aggr_v2<<<BB, 256, 0, stream>>>(partial, Wo1f, resW, resb, ffW1, labels, tvec, counts);
    // H = gelu(gelu(emb) @ W1btm + tvec + b1) -> BUF3  (A = emb fp32 + gelu)
    gemm64<1,1,1,0,2><<<dim3(128, 4), 256, 0, stream>>>(
        emb, Wt + 7 * 65536, BUF3, nullptr, ffb1, tvec);
    // F = H @ W2 + b2 (fp32)
    gemm64<0,1,0,1,0><<<dim3(128, 4), 256, 0, stream>>>(
        BUF3, Wt + 8 * 65536, nullptr, F, ffb2, nullptr);
    classsum_v2<<<dim3(BB, 4), 256, 0, stream>>>(F, labels, gsum);
    out_kernel<<<dim3(128, BB), 256, 0, stream>>>(F, labels, gsum, counts, out);
}

// Round 8
// 223.337 us; speedup vs baseline: 1.0646x; 1.0646x over previous
//
#include <hip/hip_runtime.h>

#define BB 16
#define NN 512
#define DD 256
#define HH 8
#define CC 16

typedef unsigned short u16;
using short8 = __attribute__((ext_vector_type(8))) short;
using f32x4  = __attribute__((ext_vector_type(4))) float;

__device__ __forceinline__ float gelu_f(float x) {
    return 0.5f * x * (1.0f + erff(x * 0.70710678118654752f));
}
__device__ __forceinline__ u16 f2bf(float f) {
    unsigned int u = __float_as_uint(f);
    unsigned int r = u + 0x7FFFu + ((u >> 16) & 1u);
    return (u16)(r >> 16);
}
// async global->LDS, 16B/lane; LDS dest = wave-uniform base + lane*16
__device__ __forceinline__ void gld16(const u16* g, const u16* l) {
    __builtin_amdgcn_global_load_lds(
        (const __attribute__((address_space(1))) unsigned int*)g,
        (__attribute__((address_space(3))) unsigned int*)l, 16, 0, 0);
}

// Q pre-scale: (1/sqrt(32)) * log2(e) -> attention uses exp2
#define QSCALE 0.25505412f

// ---------------------------------------------------------------------------
// QKV GEMM, 128x64 tiles, BK=32. grid (64, 12); sel = y>>2 picks Q/K/V.
// AFP32=1: A is fp32 (emb), converted to bf16 during staging with
// conflict-free writes (lane writes 16B at byte offset tid*16).
// Outputs: Q,K head-major [b,h,n,32] (Q scaled), V transposed [b,h,32,n].
// ---------------------------------------------------------------------------
template<int AFP32>
__global__ __launch_bounds__(256) void gemm_qkv128(
    const void* __restrict__ Av,
    const u16* __restrict__ W0, const u16* __restrict__ W1, const u16* __restrict__ W2,
    u16* __restrict__ O0, u16* __restrict__ O1, u16* __restrict__ O2)
{
    __shared__ __align__(16) u16 As[128 * 32];
    __shared__ __align__(16) u16 Bs[64 * 32];
    const int tid = threadIdx.x, wave = tid >> 6, lane = tid & 63;
    const int col = lane & 15, quad = lane >> 4;
    const int mbase = blockIdx.x * 128;
    const int sel = blockIdx.y >> 2;
    const int nbase = (blockIdx.y & 3) * 64;
    const u16* W = (sel == 0) ? W0 : ((sel == 1) ? W1 : W2);
    u16* O = (sel == 0) ? O0 : ((sel == 1) ? O1 : O2);
    const int srow = lane >> 2, skk = (lane & 3) * 8;
    const int mh = (wave & 1) * 64, nh = (wave >> 1) * 32;

    f32x4 acc[4][2];
#pragma unroll
    for (int i = 0; i < 4; ++i)
#pragma unroll
        for (int j = 0; j < 2; ++j) acc[i][j] = (f32x4){0.f, 0.f, 0.f, 0.f};

    for (int k0 = 0; k0 < DD; k0 += 32) {
        if (AFP32) {
            const float* Af = (const float*)Av;
#pragma unroll
            for (int it = 0; it < 2; ++it) {
                const int idx = tid * 8 + it * 2048;   // u16 index, 16B/lane
                const int row = idx >> 5, ko = idx & 31;
                const float* src = Af + (size_t)(mbase + row) * DD + k0 + ko;
                const float4 v0 = *(const float4*)(src + 0);
                const float4 v1 = *(const float4*)(src + 4);
                ushort4 w0, w1;
                w0.x = f2bf(v0.x); w0.y = f2bf(v0.y); w0.z = f2bf(v0.z); w0.w = f2bf(v0.w);
                w1.x = f2bf(v1.x); w1.y = f2bf(v1.y); w1.z = f2bf(v1.z); w1.w = f2bf(v1.w);
                *(ushort4*)&As[idx + 0] = w0;
                *(ushort4*)&As[idx + 4] = w1;
            }
        } else {
            const u16* Ab = (const u16*)Av;
#pragma unroll
            for (int c = 0; c < 2; ++c) {
                const int ch = wave * 2 + c;
                gld16(Ab + (size_t)(mbase + ch * 16 + srow) * DD + k0 + skk, &As[ch * 512]);
            }
        }
        gld16(W + (size_t)(nbase + wave * 16 + srow) * DD + k0 + skk, &Bs[wave * 512]);
        __syncthreads();
        short8 af[4], bfr[2];
#pragma unroll
        for (int i = 0; i < 4; ++i) af[i]  = *(const short8*)&As[(mh + i * 16 + col) * 32 + quad * 8];
#pragma unroll
        for (int j = 0; j < 2; ++j) bfr[j] = *(const short8*)&Bs[(nh + j * 16 + col) * 32 + quad * 8];
#pragma unroll
        for (int i = 0; i < 4; ++i)
#pragma unroll
            for (int j = 0; j < 2; ++j)
                acc[i][j] = __builtin_amdgcn_mfma_f32_16x16x32_bf16(af[i], bfr[j], acc[i][j], 0, 0, 0);
        __syncthreads();
    }

    const int b = mbase >> 9;
#pragma unroll
    for (int i = 0; i < 4; ++i) {
#pragma unroll
        for (int j = 0; j < 2; ++j) {
            const int ccol = nbase + nh + j * 16 + col;
            const int tok0 = (mbase & 511) + mh + i * 16 + quad * 4;
            const int head = ccol >> 5, dk = ccol & 31;
            if (sel == 2) {
                ushort4 pk;
                pk.x = f2bf(acc[i][j][0]); pk.y = f2bf(acc[i][j][1]);
                pk.z = f2bf(acc[i][j][2]); pk.w = f2bf(acc[i][j][3]);
                *(ushort4*)&O[(((size_t)b * HH + head) * 32 + dk) * NN + tok0] = pk;
            } else {
#pragma unroll
                for (int r = 0; r < 4; ++r) {
                    float v = acc[i][j][r];
                    if (sel == 0) v *= QSCALE;
                    O[(((size_t)b * HH + head) * NN + tok0 + r) * 32 + dk] = f2bf(v);
                }
            }
        }
    }
}

// ---------------------------------------------------------------------------
// Generic 64x64-tile bf16 MFMA GEMM (BK=32). grid (128, 4).
// AG: 0 = A bf16 (gld16), 2 = A fp32 with gelu applied during staging
// (conflict-free: lane writes 16B at byte tid*16).
// ---------------------------------------------------------------------------
template<int ACT, int HAS_B, int HAS_T, int OUT_F32, int AG>
__global__ __launch_bounds__(256) void gemm64(
    const void* __restrict__ Av, const u16* __restrict__ W,
    u16* __restrict__ O, float* __restrict__ OF,
    const float* __restrict__ bias, const float* __restrict__ tvec)
{
    __shared__ __align__(16) u16 As[64 * 32];
    __shared__ __align__(16) u16 Bs[64 * 32];
    const int tid = threadIdx.x, wave = tid >> 6, lane = tid & 63;
    const int col = lane & 15, quad = lane >> 4;
    const int mbase = blockIdx.x * 64;
    const int nbase = blockIdx.y * 64;
    const int srow = lane >> 2, skk = (lane & 3) * 8;
    const int mh = (wave & 1) * 32, nh = (wave >> 1) * 32;

    f32x4 acc[2][2];
#pragma unroll
    for (int i = 0; i < 2; ++i)
#pragma unroll
        for (int j = 0; j < 2; ++j) acc[i][j] = (f32x4){0.f, 0.f, 0.f, 0.f};

    for (int k0 = 0; k0 < DD; k0 += 32) {
        if (AG) {
            const float* Af = (const float*)Av;
            const int idx = tid * 8;               // 64 rows x 32 k = 2048 u16
            const int row = idx >> 5, ko = idx & 31;
            const float* src = Af + (size_t)(mbase + row) * DD + k0 + ko;
            const float4 v0 = *(const float4*)(src + 0);
            const float4 v1 = *(const float4*)(src + 4);
            ushort4 w0, w1;
            w0.x = f2bf(gelu_f(v0.x)); w0.y = f2bf(gelu_f(v0.y));
            w0.z = f2bf(gelu_f(v0.z)); w0.w = f2bf(gelu_f(v0.w));
            w1.x = f2bf(gelu_f(v1.x)); w1.y = f2bf(gelu_f(v1.y));
            w1.z = f2bf(gelu_f(v1.z)); w1.w = f2bf(gelu_f(v1.w));
            *(ushort4*)&As[idx + 0] = w0;
            *(ushort4*)&As[idx + 4] = w1;
        } else {
            const u16* Ab = (const u16*)Av;
            gld16(Ab + (size_t)(mbase + wave * 16 + srow) * DD + k0 + skk, &As[wave * 512]);
        }
        gld16(W + (size_t)(nbase + wave * 16 + srow) * DD + k0 + skk, &Bs[wave * 512]);
        __syncthreads();
        short8 af[2], bfr[2];
#pragma unroll
        for (int i = 0; i < 2; ++i) af[i]  = *(const short8*)&As[(mh + i * 16 + col) * 32 + quad * 8];
#pragma unroll
        for (int j = 0; j < 2; ++j) bfr[j] = *(const short8*)&Bs[(nh + j * 16 + col) * 32 + quad * 8];
#pragma unroll
        for (int i = 0; i < 2; ++i)
#pragma unroll
            for (int j = 0; j < 2; ++j)
                acc[i][j] = __builtin_amdgcn_mfma_f32_16x16x32_bf16(af[i], bfr[j], acc[i][j], 0, 0, 0);
        __syncthreads();
    }

    const int b = mbase >> 9;
#pragma unroll
    for (int i = 0; i < 2; ++i) {
#pragma unroll
        for (int j = 0; j < 2; ++j) {
            const int ccol = nbase + nh + j * 16 + col;
#pragma unroll
            for (int r = 0; r < 4; ++r) {
                const int crow = mbase + mh + i * 16 + quad * 4 + r;
                float v = acc[i][j][r];
                if (HAS_B) v += bias[ccol];
                if (HAS_T) v += tvec[b * DD + ccol];
                if (ACT)   v = gelu_f(v);
                if (OUT_F32) OF[(size_t)crow * DD + ccol] = v;
                else         O[(size_t)crow * DD + ccol] = f2bf(v);
            }
        }
    }
}

// ---------------------------------------------------------------------------
// Flash MFMA attention (round-6 version): V^T staged in LDS (shared by all
// waves), K fragments from L1/L2, no-max softmax via exp2.
// grid 1024: gid = qb*128 + (b*8+h) -> q-blocks of a (b,h) share an XCD.
// COLSUM=1: only writes per-block column sums (feeds mean(x2)@Wo1).
// ---------------------------------------------------------------------------
template<int COLSUM>
__global__ __launch_bounds__(256) void attn_mfma(
    const u16* __restrict__ Qh, const u16* __restrict__ Kh,
    const u16* __restrict__ VT, u16* __restrict__ O,
    float* __restrict__ partial)
{
    __shared__ __align__(16) u16 Vt[32 * 520];
    __shared__ __align__(16) u16 Pc[4][16 * 32];
    __shared__ float cs[4][32];
    const int tid = threadIdx.x, wave = tid >> 6, lane = tid & 63;
    const int col = lane & 15, quad = lane >> 4;
    const int gid = blockIdx.x;
    const int qb = gid >> 7, bh = gid & 127;
    const int q0 = qb * 64 + wave * 16;

    const u16* vsrc = VT + (size_t)bh * 32 * NN;
#pragma unroll
    for (int i = 0; i < 8; ++i) {
        const int row = wave + i * 4;
        gld16(vsrc + (size_t)row * NN + lane * 8, &Vt[row * 520]);
    }
    const short8 aq = *(const short8*)(Qh + ((size_t)bh * NN + q0 + col) * 32 + quad * 8);
    __syncthreads();

    const u16* ksrc = Kh + (size_t)bh * NN * 32;
    float l[4] = {0.f, 0.f, 0.f, 0.f};
    f32x4 oacc[2];
    oacc[0] = (f32x4){0.f, 0.f, 0.f, 0.f};
    oacc[1] = (f32x4){0.f, 0.f, 0.f, 0.f};

    for (int g = 0; g < 16; ++g) {
#pragma unroll
        for (int k2 = 0; k2 < 2; ++k2) {
            const int kt = g * 2 + k2;
            const short8 bk = *(const short8*)(ksrc + (size_t)(kt * 16 + col) * 32 + quad * 8);
            f32x4 z = {0.f, 0.f, 0.f, 0.f};
            const f32x4 s = __builtin_amdgcn_mfma_f32_16x16x32_bf16(aq, bk, z, 0, 0, 0);
#pragma unroll
            for (int r = 0; r < 4; ++r) {
                const float p = exp2f(s[r]);
                l[r] += p;
                Pc[wave][(quad * 4 + r) * 32 + k2 * 16 + col] = f2bf(p);
            }
        }
        const short8 ap = *(const short8*)&Pc[wave][col * 32 + quad * 8];
#pragma unroll
        for (int nt = 0; nt < 2; ++nt) {
            const short8 bv = *(const short8*)&Vt[(nt * 16 + col) * 520 + g * 32 + quad * 8];
            oacc[nt] = __builtin_amdgcn_mfma_f32_16x16x32_bf16(ap, bv, oacc[nt], 0, 0, 0);
        }
    }
#pragma unroll
    for (int r = 0; r < 4; ++r) {
        l[r] += __shfl_xor(l[r], 1, 64);
        l[r] += __shfl_xor(l[r], 2, 64);
        l[r] += __shfl_xor(l[r], 4, 64);
        l[r] += __shfl_xor(l[r], 8, 64);
    }
    if (COLSUM) {
        float sv[2] = {0.f, 0.f};
#pragma unroll
        for (int nt = 0; nt < 2; ++nt) {
#pragma unroll
            for (int r = 0; r < 4; ++r) sv[nt] += oacc[nt][r] / l[r];
            sv[nt] += __shfl_xor(sv[nt], 16, 64);
            sv[nt] += __shfl_xor(sv[nt], 32, 64);
        }
        if (lane < 16) { cs[wave][col] = sv[0]; cs[wave][16 + col] = sv[1]; }
        __syncthreads();
        if (tid < 32)
            partial[(size_t)(bh * 8 + qb) * 32 + tid] =
                cs[0][tid] + cs[1][tid] + cs[2][tid] + cs[3][tid];
    } else {
        const int b = bh >> 3, h = bh & 7;
        u16* obase = O + ((size_t)b * NN) * DD + h * 32;
#pragma unroll
        for (int nt = 0; nt < 2; ++nt)
#pragma unroll
            for (int r = 0; r < 4; ++r)
                obase[(size_t)(q0 + quad * 4 + r) * DD + nt * 16 + col] = f2bf(oacc[nt][r] / l[r]);
    }
}

// ---------------------------------------------------------------------------
// weights -> bf16, transposed [n][k]. grid 144 = 9 weights x 16 k-blocks.
// ---------------------------------------------------------------------------
__global__ __launch_bounds__(256) void convert_w(
    const float* s0, const float* s1, const float* s2, const float* s3,
    const float* s4, const float* s5, const float* s6, const float* s7,
    const float* s8, u16* __restrict__ Wt)
{
    const int w = blockIdx.x;
    const int my = w >> 4, kb = (w & 15) * 16;
    const int n = threadIdx.x;
    const float* S;
    switch (my) {
        case 0: S = s0; break; case 1: S = s1; break; case 2: S = s2; break;
        case 3: S = s3; break; case 4: S = s4; break; case 5: S = s5; break;
        case 6: S = s6; break; case 7: S = s7; break; default: S = s8; break;
    }
    u16* Dst = Wt + (size_t)my * 65536;
    for (int r = 0; r < 16; ++r) {
        const int k = kb + r;
        Dst[(size_t)n * 256 + k] = f2bf(S[(size_t)k * 256 + n]);
    }
}

// ---------------------------------------------------------------------------
// latency-unrolled matvec: 8 independent accumulator chains
// ---------------------------------------------------------------------------
__device__ __forceinline__ float mv256(const float* __restrict__ a,
                                       const float* __restrict__ W, int d)
{
    float acc[8] = {0.f, 0.f, 0.f, 0.f, 0.f, 0.f, 0.f, 0.f};
    for (int k = 0; k < 256; k += 8) {
#pragma unroll
        for (int j = 0; j < 8; ++j)
            acc[j] += a[k + j] * W[(size_t)(k + j) * 256 + d];
    }
    return ((acc[0] + acc[1]) + (acc[2] + acc[3])) + ((acc[4] + acc[5]) + (acc[6] + acc[7]));
}

__global__ __launch_bounds__(256) void aggr_v2(
    const float* __restrict__ partial, const float* __restrict__ Wo1f,
    const float* __restrict__ resW, const float* __restrict__ resb,
    const float* __restrict__ W1, const int* __restrict__ labels,
    float* __restrict__ tvec, float* __restrict__ counts)
{
    const int b = blockIdx.x, d = threadIdx.x;
    __shared__ float a0[256], a1[256], a2[256];
    __shared__ int hist[CC];
    if (d < CC) hist[d] = 0;
    const int h = d >> 5, d32 = d & 31;
    float s = 0.f;
#pragma unroll
    for (int qb = 0; qb < 8; ++qb)
        s += partial[(size_t)(((b * 8 + h) * 8) + qb) * 32 + d32];
    a0[d] = s * (1.0f / NN);
    __syncthreads();
    atomicAdd(&hist[labels[b * NN + d]], 1);
    atomicAdd(&hist[labels[b * NN + 256 + d]], 1);
    a1[d] = gelu_f(mv256(a0, Wo1f, d));
    __syncthreads();
    a2[d] = gelu_f(mv256(a1, resW, d) + resb[d]);
    __syncthreads();
    tvec[b * 256 + d] = mv256(a2, W1, d);
    if (d < CC) counts[b * CC + d] = (float)hist[d];
}

__global__ __launch_bounds__(256) void classsum_v2(
    const float* __restrict__ F, const int* __restrict__ labels,
    float* __restrict__ g)
{
    const int b = blockIdx.x, dch = blockIdx.y;
    const int t = threadIdx.x, w = t >> 6, lane = t & 63;
    __shared__ int lab[NN];
    __shared__ float gs[4][CC][64];
    lab[t] = labels[b * NN + t];
    lab[t + 256] = labels[b * NN + t + 256];
    __syncthreads();
    float acc[CC];
#pragma unroll
    for (int c = 0; c < CC; ++c) acc[c] = 0.f;
    const float* Fb = F + (size_t)b * NN * DD + dch * 64 + lane;
#pragma unroll 4
    for (int n = w * 128; n < w * 128 + 128; ++n) {
        const float v = Fb[(size_t)n * DD];
        const int lb = lab[n];
#pragma unroll
        for (int c = 0; c < CC; ++c) acc[c] += (lb == c) ? v : 0.f;
    }
#pragma unroll
    for (int c = 0; c < CC; ++c) gs[w][c][lane] = acc[c];
    __syncthreads();
#pragma unroll
    for (int i = 0; i < 4; ++i) {
        const int c = w * 4 + i;
        g[((size_t)b * CC + c) * DD + dch * 64 + lane] =
            gs[0][c][lane] + gs[1][c][lane] + gs[2][c][lane] + gs[3][c][lane];
    }
}

__global__ __launch_bounds__(256) void out_kernel(
    const float* __restrict__ F, const int* __restrict__ labels,
    const float* __restrict__ g, const float* __restrict__ counts,
    float* __restrict__ out)
{
    const int b = blockIdx.y;
    const int wave = threadIdx.x >> 6, lane = threadIdx.x & 63;
    const int n = blockIdx.x * 4 + wave;
    const float* fn = F + ((size_t)b * NN + n) * DD;
    const float* gb = g + (size_t)b * CC * DD;
    float fv[4];
#pragma unroll
    for (int i = 0; i < 4; ++i) fv[i] = fn[lane * 4 + i];
    float selfdot = 0.f;
#pragma unroll
    for (int i = 0; i < 4; ++i) selfdot += fv[i] * fv[i];
    float accs[CC];
#pragma unroll
    for (int c = 0; c < CC; ++c) {
        float sacc = 0.f;
#pragma unroll
        for (int i = 0; i < 4; ++i) sacc += fv[i] * gb[c * DD + lane * 4 + i];
        accs[c] = sacc;
    }
    for (int off = 32; off; off >>= 1) {
        selfdot += __shfl_xor(selfdot, off, 64);
#pragma unroll
        for (int c = 0; c < CC; ++c) accs[c] += __shfl_xor(accs[c], off, 64);
    }
    if (lane < CC) {
        const int c = lane;
        const int same = (labels[b * NN + n] == c) ? 1 : 0;
        const float num = accs[c] - (same ? selfdot : 0.f);
        const float den = counts[b * CC + c] - (float)same;
        out[((size_t)b * NN + n) * CC + c] = num / den;
    }
}

// ---------------------------------------------------------------------------
extern "C" void kernel_launch(void* const* d_in, const int* in_sizes, int n_in,
                              void* d_out, int out_size, void* d_ws, size_t ws_size,
                              hipStream_t stream)
{
    const float* emb    = (const float*)d_in[0];
    const int*   labels = (const int*)  d_in[1];
    const float* Wo1f = (const float*)d_in[9];
    const float* resW = (const float*)d_in[10];
    const float* resb = (const float*)d_in[11];
    const float* ffW1 = (const float*)d_in[12];
    const float* ffb1 = (const float*)d_in[13];
    const float* ffb2 = (const float*)d_in[15];
    float* out = (float*)d_out;

    const size_t SBE = (size_t)BB * NN * DD;
    u16* BUF0 = (u16*)d_ws;          // X1
    u16* BUF2 = BUF0 + SBE;          // Qh [b,h,n,32]
    u16* BUF3 = BUF2 + SBE;          // Kh, later H
    u16* BUF4 = BUF3 + SBE;          // VT [b,h,32,n]
    u16* BUF5 = BUF4 + SBE;          // attn0 out (token-major)
    u16* Wt   = BUF5 + SBE;          // 9 x [256n x 256k] bf16 transposed
    float* F      = (float*)(Wt + 9 * 65536);   // [8192x256] fp32 features
    float* tvec   = F + SBE;
    float* partial= tvec + BB * 256;            // [128 bh][8 qb][32]
    float* gsum   = partial + 128 * 8 * 32;
    float* counts = gsum + (size_t)BB * CC * DD;

    convert_w<<<144, 256, 0, stream>>>(
        (const float*)d_in[2], (const float*)d_in[3], (const float*)d_in[4],
        (const float*)d_in[5], (const float*)d_in[6], (const float*)d_in[7],
        (const float*)d_in[8], ffW1 + 256 * 256, (const float*)d_in[14], Wt);
    // QKV0 (A = emb fp32, converted during staging, conflict-free writes)
    gemm_qkv128<1><<<dim3(64, 12), 256, 0, stream>>>(
        emb, Wt, Wt + 65536, Wt + 2 * 65536, BUF2, BUF3, BUF4);
    attn_mfma<0><<<1024, 256, 0, stream>>>(BUF2, BUF3, BUF4, BUF5, nullptr);
    // X1 = gelu(attn0 @ Wo0) -> BUF0
    gemm64<1,0,0,0,0><<<dim3(128, 4), 256, 0, stream>>>(
        BUF5, Wt + 3 * 65536, BUF0, nullptr, nullptr, nullptr);
    // QKV1 (A = X1 bf16 via gld16)
    gemm_qkv128<0><<<dim3(64, 12), 256, 0, stream>>>(
        BUF0, Wt + 4 * 65536, Wt + 5 * 65536, Wt + 6 * 65536, BUF2, BUF3, BUF4);
    // attn1: column sums only
    attn_mfma<1><<<1024, 256, 0, stream>>>(BUF2, BUF3, BUF4, nullptr, partial);
    aggr_v2<<<BB, 256, 0, stream>>>(partial, Wo1f, resW, resb, ffW1, labels, tvec, counts);
    // H = gelu(gelu(emb) @ W1btm + tvec + b1) -> BUF3 (fp32+gelu staging)
    gemm64<1,1,1,0,2><<<dim3(128, 4), 256, 0, stream>>>(
        emb, Wt + 7 * 65536, BUF3, nullptr, ffb1, tvec);
    // F = H @ W2 + b2 (fp32)
    gemm64<0,1,0,1,0><<<dim3(128, 4), 256, 0, stream>>>(
        BUF3, Wt + 8 * 65536, nullptr, F, ffb2, nullptr);
    classsum_v2<<<dim3(BB, 4), 256, 0, stream>>>(F, labels, gsum);
    out_kernel<<<dim3(128, BB), 256, 0, stream>>>(F, labels, gsum, counts, out);
}

// Round 9
// 214.176 us; speedup vs baseline: 1.1102x; 1.0428x over previous
//
#include <hip/hip_runtime.h>

#define BB 16
#define NN 512
#define DD 256
#define HH 8
#define CC 16

typedef unsigned short u16;
using short8 = __attribute__((ext_vector_type(8))) short;
using f32x4  = __attribute__((ext_vector_type(4))) float;

__device__ __forceinline__ float gelu_f(float x) {
    return 0.5f * x * (1.0f + erff(x * 0.70710678118654752f));
}
__device__ __forceinline__ u16 f2bf(float f) {
    unsigned int u = __float_as_uint(f);
    unsigned int r = u + 0x7FFFu + ((u >> 16) & 1u);
    return (u16)(r >> 16);
}
// async global->LDS, 16B/lane; LDS dest = wave-uniform base + lane*16
__device__ __forceinline__ void gld16(const u16* g, const u16* l) {
    __builtin_amdgcn_global_load_lds(
        (const __attribute__((address_space(1))) unsigned int*)g,
        (__attribute__((address_space(3))) unsigned int*)l, 16, 0, 0);
}

// Q pre-scale: (1/sqrt(32)) * log2(e) -> attention uses exp2
#define QSCALE 0.25505412f

// ---------------------------------------------------------------------------
// QKV GEMM v3: one block computes Q, K AND V for its 64x64 tile (A staged
// once, 3x MFMA per barrier pair). BK=64 as two BK=32 panels (fragment
// addressing identical to the proven 64x64 kernel). grid (128, 4).
// Outputs: Q,K head-major [b,h,n,32] (Q scaled), V transposed [b,h,32,n].
// ---------------------------------------------------------------------------
__global__ __launch_bounds__(256) void gemm_qkv3(
    const u16* __restrict__ A,
    const u16* __restrict__ W0, const u16* __restrict__ W1, const u16* __restrict__ W2,
    u16* __restrict__ O0, u16* __restrict__ O1, u16* __restrict__ O2)
{
    __shared__ __align__(16) u16 As[2][64 * 32];
    __shared__ __align__(16) u16 Bs[3][2][64 * 32];
    const int tid = threadIdx.x, wave = tid >> 6, lane = tid & 63;
    const int col = lane & 15, quad = lane >> 4;
    const int mbase = blockIdx.x * 64;
    const int nbase = blockIdx.y * 64;
    const int srow = lane >> 2, skk = (lane & 3) * 8;
    const int mh = (wave & 1) * 32, nh = (wave >> 1) * 32;
    const u16* Ws[3] = {W0, W1, W2};

    f32x4 acc[3][2][2];
#pragma unroll
    for (int s = 0; s < 3; ++s)
#pragma unroll
        for (int i = 0; i < 2; ++i)
#pragma unroll
            for (int j = 0; j < 2; ++j) acc[s][i][j] = (f32x4){0.f, 0.f, 0.f, 0.f};

    for (int k0 = 0; k0 < DD; k0 += 64) {
#pragma unroll
        for (int p = 0; p < 2; ++p) {
            gld16(A + (size_t)(mbase + wave * 16 + srow) * DD + k0 + p * 32 + skk,
                  &As[p][wave * 512]);
#pragma unroll
            for (int s = 0; s < 3; ++s)
                gld16(Ws[s] + (size_t)(nbase + wave * 16 + srow) * DD + k0 + p * 32 + skk,
                      &Bs[s][p][wave * 512]);
        }
        __syncthreads();
#pragma unroll
        for (int p = 0; p < 2; ++p) {
            short8 af[2];
#pragma unroll
            for (int i = 0; i < 2; ++i)
                af[i] = *(const short8*)&As[p][(mh + i * 16 + col) * 32 + quad * 8];
#pragma unroll
            for (int s = 0; s < 3; ++s) {
                short8 bfr[2];
#pragma unroll
                for (int j = 0; j < 2; ++j)
                    bfr[j] = *(const short8*)&Bs[s][p][(nh + j * 16 + col) * 32 + quad * 8];
#pragma unroll
                for (int i = 0; i < 2; ++i)
#pragma unroll
                    for (int j = 0; j < 2; ++j)
                        acc[s][i][j] = __builtin_amdgcn_mfma_f32_16x16x32_bf16(
                            af[i], bfr[j], acc[s][i][j], 0, 0, 0);
            }
        }
        __syncthreads();
    }

    const int b = mbase >> 9;
#pragma unroll
    for (int s = 0; s < 3; ++s) {
        u16* O = (s == 0) ? O0 : ((s == 1) ? O1 : O2);
#pragma unroll
        for (int i = 0; i < 2; ++i) {
#pragma unroll
            for (int j = 0; j < 2; ++j) {
                const int ccol = nbase + nh + j * 16 + col;
                const int tok0 = (mbase & 511) + mh + i * 16 + quad * 4;
                const int head = ccol >> 5, dk = ccol & 31;
                if (s == 2) {
                    ushort4 pk;
                    pk.x = f2bf(acc[s][i][j][0]); pk.y = f2bf(acc[s][i][j][1]);
                    pk.z = f2bf(acc[s][i][j][2]); pk.w = f2bf(acc[s][i][j][3]);
                    *(ushort4*)&O[(((size_t)b * HH + head) * 32 + dk) * NN + tok0] = pk;
                } else {
#pragma unroll
                    for (int r = 0; r < 4; ++r) {
                        float v = acc[s][i][j][r];
                        if (s == 0) v *= QSCALE;
                        O[(((size_t)b * HH + head) * NN + tok0 + r) * 32 + dk] = f2bf(v);
                    }
                }
            }
        }
    }
}

// ---------------------------------------------------------------------------
// Generic 64x64-tile bf16 MFMA GEMM, BK=64 (two BK=32 panels). grid (128, 4).
// ---------------------------------------------------------------------------
template<int ACT, int HAS_B, int HAS_T, int OUT_F32>
__global__ __launch_bounds__(256) void gemm64(
    const u16* __restrict__ A, const u16* __restrict__ W,
    u16* __restrict__ O, float* __restrict__ OF,
    const float* __restrict__ bias, const float* __restrict__ tvec)
{
    __shared__ __align__(16) u16 As[2][64 * 32];
    __shared__ __align__(16) u16 Bs[2][64 * 32];
    const int tid = threadIdx.x, wave = tid >> 6, lane = tid & 63;
    const int col = lane & 15, quad = lane >> 4;
    const int mbase = blockIdx.x * 64;
    const int nbase = blockIdx.y * 64;
    const int srow = lane >> 2, skk = (lane & 3) * 8;
    const int mh = (wave & 1) * 32, nh = (wave >> 1) * 32;

    f32x4 acc[2][2];
#pragma unroll
    for (int i = 0; i < 2; ++i)
#pragma unroll
        for (int j = 0; j < 2; ++j) acc[i][j] = (f32x4){0.f, 0.f, 0.f, 0.f};

    for (int k0 = 0; k0 < DD; k0 += 64) {
#pragma unroll
        for (int p = 0; p < 2; ++p) {
            gld16(A + (size_t)(mbase + wave * 16 + srow) * DD + k0 + p * 32 + skk,
                  &As[p][wave * 512]);
            gld16(W + (size_t)(nbase + wave * 16 + srow) * DD + k0 + p * 32 + skk,
                  &Bs[p][wave * 512]);
        }
        __syncthreads();
#pragma unroll
        for (int p = 0; p < 2; ++p) {
            short8 af[2], bfr[2];
#pragma unroll
            for (int i = 0; i < 2; ++i)
                af[i] = *(const short8*)&As[p][(mh + i * 16 + col) * 32 + quad * 8];
#pragma unroll
            for (int j = 0; j < 2; ++j)
                bfr[j] = *(const short8*)&Bs[p][(nh + j * 16 + col) * 32 + quad * 8];
#pragma unroll
            for (int i = 0; i < 2; ++i)
#pragma unroll
                for (int j = 0; j < 2; ++j)
                    acc[i][j] = __builtin_amdgcn_mfma_f32_16x16x32_bf16(
                        af[i], bfr[j], acc[i][j], 0, 0, 0);
        }
        __syncthreads();
    }

    const int b = mbase >> 9;
#pragma unroll
    for (int i = 0; i < 2; ++i) {
#pragma unroll
        for (int j = 0; j < 2; ++j) {
            const int ccol = nbase + nh + j * 16 + col;
#pragma unroll
            for (int r = 0; r < 4; ++r) {
                const int crow = mbase + mh + i * 16 + quad * 4 + r;
                float v = acc[i][j][r];
                if (HAS_B) v += bias[ccol];
                if (HAS_T) v += tvec[b * DD + ccol];
                if (ACT)   v = gelu_f(v);
                if (OUT_F32) OF[(size_t)crow * DD + ccol] = v;
                else         O[(size_t)crow * DD + ccol] = f2bf(v);
            }
        }
    }
}

// ---------------------------------------------------------------------------
// Flash MFMA attention (round-6 version): V^T staged in LDS, K fragments
// from L1/L2, no-max softmax via exp2 (scores pre-scaled by log2e/sqrt(dk)).
// grid 1024: gid = qb*128 + (b*8+h) -> q-blocks of a (b,h) share an XCD.
// COLSUM=1: only writes per-block column sums (feeds mean(x2)@Wo1).
// ---------------------------------------------------------------------------
template<int COLSUM>
__global__ __launch_bounds__(256) void attn_mfma(
    const u16* __restrict__ Qh, const u16* __restrict__ Kh,
    const u16* __restrict__ VT, u16* __restrict__ O,
    float* __restrict__ partial)
{
    __shared__ __align__(16) u16 Vt[32 * 520];
    __shared__ __align__(16) u16 Pc[4][16 * 32];
    __shared__ float cs[4][32];
    const int tid = threadIdx.x, wave = tid >> 6, lane = tid & 63;
    const int col = lane & 15, quad = lane >> 4;
    const int gid = blockIdx.x;
    const int qb = gid >> 7, bh = gid & 127;
    const int q0 = qb * 64 + wave * 16;

    const u16* vsrc = VT + (size_t)bh * 32 * NN;
#pragma unroll
    for (int i = 0; i < 8; ++i) {
        const int row = wave + i * 4;
        gld16(vsrc + (size_t)row * NN + lane * 8, &Vt[row * 520]);
    }
    const short8 aq = *(const short8*)(Qh + ((size_t)bh * NN + q0 + col) * 32 + quad * 8);
    __syncthreads();

    const u16* ksrc = Kh + (size_t)bh * NN * 32;
    float l[4] = {0.f, 0.f, 0.f, 0.f};
    f32x4 oacc[2];
    oacc[0] = (f32x4){0.f, 0.f, 0.f, 0.f};
    oacc[1] = (f32x4){0.f, 0.f, 0.f, 0.f};

    for (int g = 0; g < 16; ++g) {
#pragma unroll
        for (int k2 = 0; k2 < 2; ++k2) {
            const int kt = g * 2 + k2;
            const short8 bk = *(const short8*)(ksrc + (size_t)(kt * 16 + col) * 32 + quad * 8);
            f32x4 z = {0.f, 0.f, 0.f, 0.f};
            const f32x4 s = __builtin_amdgcn_mfma_f32_16x16x32_bf16(aq, bk, z, 0, 0, 0);
#pragma unroll
            for (int r = 0; r < 4; ++r) {
                const float p = exp2f(s[r]);
                l[r] += p;
                Pc[wave][(quad * 4 + r) * 32 + k2 * 16 + col] = f2bf(p);
            }
        }
        const short8 ap = *(const short8*)&Pc[wave][col * 32 + quad * 8];
#pragma unroll
        for (int nt = 0; nt < 2; ++nt) {
            const short8 bv = *(const short8*)&Vt[(nt * 16 + col) * 520 + g * 32 + quad * 8];
            oacc[nt] = __builtin_amdgcn_mfma_f32_16x16x32_bf16(ap, bv, oacc[nt], 0, 0, 0);
        }
    }
#pragma unroll
    for (int r = 0; r < 4; ++r) {
        l[r] += __shfl_xor(l[r], 1, 64);
        l[r] += __shfl_xor(l[r], 2, 64);
        l[r] += __shfl_xor(l[r], 4, 64);
        l[r] += __shfl_xor(l[r], 8, 64);
    }
    if (COLSUM) {
        float sv[2] = {0.f, 0.f};
#pragma unroll
        for (int nt = 0; nt < 2; ++nt) {
#pragma unroll
            for (int r = 0; r < 4; ++r) sv[nt] += oacc[nt][r] / l[r];
            sv[nt] += __shfl_xor(sv[nt], 16, 64);
            sv[nt] += __shfl_xor(sv[nt], 32, 64);
        }
        if (lane < 16) { cs[wave][col] = sv[0]; cs[wave][16 + col] = sv[1]; }
        __syncthreads();
        if (tid < 32)
            partial[(size_t)(bh * 8 + qb) * 32 + tid] =
                cs[0][tid] + cs[1][tid] + cs[2][tid] + cs[3][tid];
    } else {
        const int b = bh >> 3, h = bh & 7;
        u16* obase = O + ((size_t)b * NN) * DD + h * 32;
#pragma unroll
        for (int nt = 0; nt < 2; ++nt)
#pragma unroll
            for (int r = 0; r < 4; ++r)
                obase[(size_t)(q0 + quad * 4 + r) * DD + nt * 16 + col] = f2bf(oacc[nt][r] / l[r]);
    }
}

// ---------------------------------------------------------------------------
// merged conversion: blocks [0,2048) emb -> E_bf + gelu(E)_bf;
// blocks [2048, 2048+144): 9 weights transposed to bf16 [n][k]
// ---------------------------------------------------------------------------
__global__ __launch_bounds__(256) void convert_all(
    const float* __restrict__ e, u16* __restrict__ E, u16* __restrict__ G,
    const float* s0, const float* s1, const float* s2, const float* s3,
    const float* s4, const float* s5, const float* s6, const float* s7,
    const float* s8, u16* __restrict__ Wt)
{
    const int bx = blockIdx.x;
    if (bx < 2048) {
        const size_t i = ((size_t)bx * 256 + threadIdx.x) * 4;
        const float4 v = *(const float4*)(e + i);
        ushort4 ev, gv;
        ev.x = f2bf(v.x); ev.y = f2bf(v.y); ev.z = f2bf(v.z); ev.w = f2bf(v.w);
        gv.x = f2bf(gelu_f(v.x)); gv.y = f2bf(gelu_f(v.y));
        gv.z = f2bf(gelu_f(v.z)); gv.w = f2bf(gelu_f(v.w));
        *(ushort4*)(E + i) = ev;
        *(ushort4*)(G + i) = gv;
    } else {
        const int w = bx - 2048;
        const int my = w >> 4, kb = (w & 15) * 16;
        const int n = threadIdx.x;
        const float* S;
        switch (my) {
            case 0: S = s0; break; case 1: S = s1; break; case 2: S = s2; break;
            case 3: S = s3; break; case 4: S = s4; break; case 5: S = s5; break;
            case 6: S = s6; break; case 7: S = s7; break; default: S = s8; break;
        }
        u16* Dst = Wt + (size_t)my * 65536;
        for (int r = 0; r < 16; ++r) {
            const int k = kb + r;
            Dst[(size_t)n * 256 + k] = f2bf(S[(size_t)k * 256 + n]);
        }
    }
}

// ---------------------------------------------------------------------------
// latency-unrolled matvec: 8 independent accumulator chains
// ---------------------------------------------------------------------------
__device__ __forceinline__ float mv256(const float* __restrict__ a,
                                       const float* __restrict__ W, int d)
{
    float acc[8] = {0.f, 0.f, 0.f, 0.f, 0.f, 0.f, 0.f, 0.f};
    for (int k = 0; k < 256; k += 8) {
#pragma unroll
        for (int j = 0; j < 8; ++j)
            acc[j] += a[k + j] * W[(size_t)(k + j) * 256 + d];
    }
    return ((acc[0] + acc[1]) + (acc[2] + acc[3])) + ((acc[4] + acc[5]) + (acc[6] + acc[7]));
}

__global__ __launch_bounds__(256) void aggr_v2(
    const float* __restrict__ partial, const float* __restrict__ Wo1f,
    const float* __restrict__ resW, const float* __restrict__ resb,
    const float* __restrict__ W1, const int* __restrict__ labels,
    float* __restrict__ tvec, float* __restrict__ counts)
{
    const int b = blockIdx.x, d = threadIdx.x;
    __shared__ float a0[256], a1[256], a2[256];
    __shared__ int hist[CC];
    if (d < CC) hist[d] = 0;
    const int h = d >> 5, d32 = d & 31;
    float s = 0.f;
#pragma unroll
    for (int qb = 0; qb < 8; ++qb)
        s += partial[(size_t)(((b * 8 + h) * 8) + qb) * 32 + d32];
    a0[d] = s * (1.0f / NN);
    __syncthreads();
    atomicAdd(&hist[labels[b * NN + d]], 1);
    atomicAdd(&hist[labels[b * NN + 256 + d]], 1);
    a1[d] = gelu_f(mv256(a0, Wo1f, d));
    __syncthreads();
    a2[d] = gelu_f(mv256(a1, resW, d) + resb[d]);
    __syncthreads();
    tvec[b * 256 + d] = mv256(a2, W1, d);
    if (d < CC) counts[b * CC + d] = (float)hist[d];
}

__global__ __launch_bounds__(256) void classsum_v2(
    const float* __restrict__ F, const int* __restrict__ labels,
    float* __restrict__ g)
{
    const int b = blockIdx.x, dch = blockIdx.y;
    const int t = threadIdx.x, w = t >> 6, lane = t & 63;
    __shared__ int lab[NN];
    __shared__ float gs[4][CC][64];
    lab[t] = labels[b * NN + t];
    lab[t + 256] = labels[b * NN + t + 256];
    __syncthreads();
    float acc[CC];
#pragma unroll
    for (int c = 0; c < CC; ++c) acc[c] = 0.f;
    const float* Fb = F + (size_t)b * NN * DD + dch * 64 + lane;
#pragma unroll 4
    for (int n = w * 128; n < w * 128 + 128; ++n) {
        const float v = Fb[(size_t)n * DD];
        const int lb = lab[n];
#pragma unroll
        for (int c = 0; c < CC; ++c) acc[c] += (lb == c) ? v : 0.f;
    }
#pragma unroll
    for (int c = 0; c < CC; ++c) gs[w][c][lane] = acc[c];
    __syncthreads();
#pragma unroll
    for (int i = 0; i < 4; ++i) {
        const int c = w * 4 + i;
        g[((size_t)b * CC + c) * DD + dch * 64 + lane] =
            gs[0][c][lane] + gs[1][c][lane] + gs[2][c][lane] + gs[3][c][lane];
    }
}

__global__ __launch_bounds__(256) void out_kernel(
    const float* __restrict__ F, const int* __restrict__ labels,
    const float* __restrict__ g, const float* __restrict__ counts,
    float* __restrict__ out)
{
    const int b = blockIdx.y;
    const int wave = threadIdx.x >> 6, lane = threadIdx.x & 63;
    const int n = blockIdx.x * 4 + wave;
    const float* fn = F + ((size_t)b * NN + n) * DD;
    const float* gb = g + (size_t)b * CC * DD;
    float fv[4];
#pragma unroll
    for (int i = 0; i < 4; ++i) fv[i] = fn[lane * 4 + i];
    float selfdot = 0.f;
#pragma unroll
    for (int i = 0; i < 4; ++i) selfdot += fv[i] * fv[i];
    float accs[CC];
#pragma unroll
    for (int c = 0; c < CC; ++c) {
        float sacc = 0.f;
#pragma unroll
        for (int i = 0; i < 4; ++i) sacc += fv[i] * gb[c * DD + lane * 4 + i];
        accs[c] = sacc;
    }
    for (int off = 32; off; off >>= 1) {
        selfdot += __shfl_xor(selfdot, off, 64);
#pragma unroll
        for (int c = 0; c < CC; ++c) accs[c] += __shfl_xor(accs[c], off, 64);
    }
    if (lane < CC) {
        const int c = lane;
        const int same = (labels[b * NN + n] == c) ? 1 : 0;
        const float num = accs[c] - (same ? selfdot : 0.f);
        const float den = counts[b * CC + c] - (float)same;
        out[((size_t)b * NN + n) * CC + c] = num / den;
    }
}

// ---------------------------------------------------------------------------
extern "C" void kernel_launch(void* const* d_in, const int* in_sizes, int n_in,
                              void* d_out, int out_size, void* d_ws, size_t ws_size,
                              hipStream_t stream)
{
    const float* emb    = (const float*)d_in[0];
    const int*   labels = (const int*)  d_in[1];
    const float* Wo1f = (const float*)d_in[9];
    const float* resW = (const float*)d_in[10];
    const float* resb = (const float*)d_in[11];
    const float* ffW1 = (const float*)d_in[12];
    const float* ffb1 = (const float*)d_in[13];
    const float* ffb2 = (const float*)d_in[15];
    float* out = (float*)d_out;

    const size_t SBE = (size_t)BB * NN * DD;
    u16* BUF0 = (u16*)d_ws;          // E_bf, later X1
    u16* BUF1 = BUF0 + SBE;          // gelu(emb) bf16
    u16* BUF2 = BUF1 + SBE;          // Qh [b,h,n,32]
    u16* BUF3 = BUF2 + SBE;          // Kh, later H
    u16* BUF4 = BUF3 + SBE;          // VT [b,h,32,n]
    u16* BUF5 = BUF4 + SBE;          // attn0 out (token-major)
    u16* Wt   = BUF5 + SBE;          // 9 x [256n x 256k] bf16 transposed
    float* F      = (float*)(Wt + 9 * 65536);   // [8192x256] fp32 features
    float* tvec   = F + SBE;
    float* partial= tvec + BB * 256;            // [128 bh][8 qb][32]
    float* gsum   = partial + 128 * 8 * 32;
    float* counts = gsum + (size_t)BB * CC * DD;

    convert_all<<<2048 + 144, 256, 0, stream>>>(
        emb, BUF0, BUF1,
        (const float*)d_in[2], (const float*)d_in[3], (const float*)d_in[4],
        (const float*)d_in[5], (const float*)d_in[6], (const float*)d_in[7],
        (const float*)d_in[8], ffW1 + 256 * 256, (const float*)d_in[14], Wt);
    // QKV0: one kernel, all three projections per tile
    gemm_qkv3<<<dim3(128, 4), 256, 0, stream>>>(
        BUF0, Wt, Wt + 65536, Wt + 2 * 65536, BUF2, BUF3, BUF4);
    attn_mfma<0><<<1024, 256, 0, stream>>>(BUF2, BUF3, BUF4, BUF5, nullptr);
    // X1 = gelu(attn0 @ Wo0) -> BUF0
    gemm64<1,0,0,0><<<dim3(128, 4), 256, 0, stream>>>(
        BUF5, Wt + 3 * 65536, BUF0, nullptr, nullptr, nullptr);
    // QKV1
    gemm_qkv3<<<dim3(128, 4), 256, 0, stream>>>(
        BUF0, Wt + 4 * 65536, Wt + 5 * 65536, Wt + 6 * 65536, BUF2, BUF3, BUF4);
    // attn1: column sums only
    attn_mfma<1><<<1024, 256, 0, stream>>>(BUF2, BUF3, BUF4, nullptr, partial);
    aggr_v2<<<BB, 256, 0, stream>>>(partial, Wo1f, resW, resb, ffW1, labels, tvec, counts);
    // H = gelu(gelu(emb) @ W1btm + tvec + b1) -> BUF3
    gemm64<1,1,1,0><<<dim3(128, 4), 256, 0, stream>>>(
        BUF1, Wt + 7 * 65536, BUF3, nullptr, ffb1, tvec);
    // F = H @ W2 + b2 (fp32)
    gemm64<0,1,0,1><<<dim3(128, 4), 256, 0, stream>>>(
        BUF3, Wt + 8 * 65536, nullptr, F, ffb2, nullptr);
    classsum_v2<<<dim3(BB, 4), 256, 0, stream>>>(F, labels, gsum);
    out_kernel<<<dim3(128, BB), 256, 0, stream>>>(F, labels, gsum, counts, out);
}